// Round 4
// baseline (348.140 us; speedup 1.0000x reference)
//
#include <hip/hip_runtime.h>
#include <hip/hip_bf16.h>

#define PI2 6.283185307179586f

typedef __attribute__((ext_vector_type(8))) short short8;
typedef __attribute__((ext_vector_type(4))) float f32x4;

// ---------------- workspace layout (float offsets) ----------------
static const size_t O_Y      = 0;          // 9*4096 harmonics
static const size_t O_W1RT   = 36864;      // 512  w1 real, transposed [c][j]
static const size_t O_W1IT   = 37376;      // 512
static const size_t O_W1XR   = 37888;      // 512  (w1 @ w_fno) real [c][j]
static const size_t O_W1XI   = 38400;      // 512
static const size_t O_B1PR   = 38912;      // 16   w1@b_fno + b1
static const size_t O_B1PI   = 38928;      // 16
static const size_t O_WSH    = 38944;      // 16   1/sqrt(cnt)
static const size_t O_SHELL  = 38960;      // int[4096]
static const size_t O_ORDER  = 43056;      // int[4096]
static const size_t O_SSTART = 47152;      // int[32]
static const size_t O_COEF   = 47232;      // 2*32*144*2
static const size_t O_COEF2  = 65664;      // 2*32*144*2
static const size_t O_XS     = 84096;      // 2*32*4096*2
static const size_t O_YW     = 608384;     // 4096*10 sorted basis, wsh-premultiplied
static const size_t O_T2     = 1132672;    // U1: 2*32*64*16*16*2 fp32
static const size_t O_T1     = 3229824;    // U2pk: 4.2M u32 (packed bf16 re/im)

static __device__ __forceinline__ float geluf(float v) {
  float u = 0.7978845608028654f * (v + 0.044715f * v * v * v);
  float a = fabsf(u);
  float e = __expf(-2.0f * a);
  float th = (1.0f - e) / (1.0f + e);
  th = copysignf(th, u);
  return 0.5f * v * (1.0f + th);
}

static __device__ __forceinline__ unsigned int f2bfbits(float f) {
  unsigned int u = __float_as_uint(f);
  u += 0x7fffu + ((u >> 16) & 1u);
  return u >> 16;
}
static __device__ __forceinline__ unsigned int pk2(float a, float b) {
  return f2bfbits(a) | (f2bfbits(b) << 16);
}

// ---------------- K0: tables + folded weights (1 block) ----------------
__global__ __launch_bounds__(256) void k0_init(
    const float* __restrict__ wfr, const float* __restrict__ wfi,
    const float* __restrict__ bfr, const float* __restrict__ bfi,
    const float* __restrict__ w1r, const float* __restrict__ w1i,
    const float* __restrict__ b1r, const float* __restrict__ b1i,
    float* __restrict__ ws) {
  float* Y    = ws + O_Y;
  float* w1rt = ws + O_W1RT;  float* w1it = ws + O_W1IT;
  float* W1xr = ws + O_W1XR;  float* W1xi = ws + O_W1XI;
  float* b1pr = ws + O_B1PR;  float* b1pi = ws + O_B1PI;
  float* wsh  = ws + O_WSH;
  float* Yw   = ws + O_YW;
  int* shellOf = (int*)(ws + O_SHELL);
  int* order   = (int*)(ws + O_ORDER);
  int* sstart  = (int*)(ws + O_SSTART);

  __shared__ int cnt[16], fill[16], st[17];
  int tid = threadIdx.x;
  if (tid < 16) { cnt[tid] = 0; fill[tid] = 0; }
  __syncthreads();
  for (int m = tid; m < 4096; m += 256) {
    int ix = m >> 8, iy = (m >> 4) & 15, iz = m & 15;
    float kx = (float)(ix < 8 ? ix : ix - 16);
    float ky = (float)(iy < 8 ? iy : iy - 16);
    float kz = (float)(iz < 8 ? iz : iz - 16);
    float r2 = kx*kx + ky*ky + kz*kz;
    float r  = sqrtf(r2);
    float nzm = r2 > 0.f ? 1.f : 0.f;
    float inv = r2 > 0.f ? 1.0f / fmaxf(r, 1e-9f) : 0.f;
    float ux = kx*inv, uy = ky*inv, uz = kz*inv;
    Y[0*4096+m] = 0.282095f;
    Y[1*4096+m] = 0.488603f * uy;
    Y[2*4096+m] = 0.488603f * uz;
    Y[3*4096+m] = 0.488603f * ux;
    Y[4*4096+m] = 1.092548f * ux*uy;
    Y[5*4096+m] = 1.092548f * uy*uz;
    Y[6*4096+m] = 0.315392f * (3.0f*uz*uz - nzm);
    Y[7*4096+m] = 1.092548f * ux*uz;
    Y[8*4096+m] = 0.546274f * (ux*ux - uy*uy);
    float rmax = sqrtf(192.0f);
    float t = r / (rmax + 1e-6f) * 16.0f;
    int sh = (int)t; sh = sh > 15 ? 15 : sh;
    shellOf[m] = sh;
    atomicAdd(&cnt[sh], 1);
  }
  __syncthreads();
  if (tid == 0) { int a = 0; for (int s = 0; s < 16; ++s) { st[s] = a; a += cnt[s]; } st[16] = a; }
  __syncthreads();
  if (tid < 16) wsh[tid] = 1.0f / sqrtf(fmaxf((float)cnt[tid], 1.0f));
  if (tid < 17) sstart[tid] = st[tid];
  for (int m = tid; m < 4096; m += 256) {
    int sh = shellOf[m];
    int p = atomicAdd(&fill[sh], 1);
    order[st[sh] + p] = m;
  }
  __syncthreads();
  // sorted, wsh-premultiplied basis rows (pos-major, 10-float stride)
  for (int pos = tid; pos < 4096; pos += 256) {
    int m = order[pos];
    float w = wsh[shellOf[m]];
    #pragma unroll
    for (int l = 0; l < 9; ++l) Yw[pos*10 + l] = w * Y[l*4096 + m];
    Yw[pos*10 + 9] = 0.f;
  }
  // fold skip_fno into the MLP: W1x = w1 @ w_fno, b1p = w1 @ b_fno + b1
  for (int e = tid; e < 512; e += 256) {
    int j = e >> 5, c = e & 31;
    float ar = 0.f, ai = 0.f;
    for (int o = 0; o < 32; ++o) {
      float wr_ = w1r[j*32+o], wi_ = w1i[j*32+o];
      float fr  = wfr[o*32+c], fi_ = wfi[o*32+c];
      ar += wr_*fr - wi_*fi_;
      ai += wr_*fi_ + wi_*fr;
    }
    W1xr[c*16+j] = ar;  W1xi[c*16+j] = ai;
    w1rt[c*16+j] = w1r[j*32+c];
    w1it[c*16+j] = w1i[j*32+c];
  }
  if (tid < 16) {
    int j = tid;
    float ar = b1r[j], ai = b1i[j];
    for (int o = 0; o < 32; ++o) {
      ar += w1r[j*32+o]*bfr[o] - w1i[j*32+o]*bfi[o];
      ai += w1r[j*32+o]*bfi[o] + w1i[j*32+o]*bfr[o];
    }
    b1pr[j] = ar; b1pi[j] = ai;
  }
}

// ---------------- K12: fused forward partial DFT z then y (real-input fold) ----------------
// grid 4096 = (b*32+c)*64 + x ; x[bc][x][y][z] -> T2[bc][x][ky][kz]
__global__ __launch_bounds__(256) void k12_fwd(const float* __restrict__ x, float* __restrict__ T2) {
  __shared__ float plane[64*68];            // [z][y]
  __shared__ float2 slab[64*17];            // [y][kz]
  int blk = blockIdx.x;
  const float* src = x + (size_t)blk * 4096;
  int tid = threadIdx.x;
  for (int i = tid; i < 4096; i += 256) {
    int y = i >> 6, z = i & 63;
    plane[z*68 + y] = src[i];
  }
  __syncthreads();
  // in-place fold: plane[z] <- x[z]+x[64-z]; plane[64-z] <- x[z]-x[64-z]  (z=1..31)
  for (int i = tid; i < 1984; i += 256) {
    int z = (i >> 6) + 1, y = i & 63;
    float a = plane[z*68 + y], bb = plane[(64 - z)*68 + y];
    plane[z*68 + y]        = a + bb;
    plane[(64 - z)*68 + y] = a - bb;
  }
  __syncthreads();
  // stage 1: z-DFT via cos/sin sums with Chebyshev recurrence
  {
    int kz = tid & 15, yq = tid >> 4;
    float f = (float)(kz < 8 ? kz : kz - 16);
    float s1, c1; __sincosf(PI2 * f * 0.015625f, &s1, &c1);
    float tc = 2.0f * c1;
    float sg = (kz & 1) ? -1.0f : 1.0f;
    float4 x0  = *(const float4*)&plane[0*68  + 4*yq];
    float4 x32 = *(const float4*)&plane[32*68 + 4*yq];
    float r0 = x0.x + sg*x32.x, r1 = x0.y + sg*x32.y;
    float r2 = x0.z + sg*x32.z, r3 = x0.w + sg*x32.w;
    float i0 = 0.f, i1 = 0.f, i2 = 0.f, i3 = 0.f;
    float cp = 1.0f, cc = c1, sp = 0.0f, sc = s1;
    for (int z = 1; z <= 31; ++z) {
      float4 sv = *(const float4*)&plane[z*68 + 4*yq];
      float4 dv = *(const float4*)&plane[(64 - z)*68 + 4*yq];
      r0 += sv.x*cc; r1 += sv.y*cc; r2 += sv.z*cc; r3 += sv.w*cc;
      i0 -= dv.x*sc; i1 -= dv.y*sc; i2 -= dv.z*sc; i3 -= dv.w*sc;
      float cn = tc*cc - cp; cp = cc; cc = cn;
      float sn = tc*sc - sp; sp = sc; sc = sn;
    }
    int y0 = 4*yq;
    slab[(y0+0)*17 + kz] = make_float2(r0, i0);
    slab[(y0+1)*17 + kz] = make_float2(r1, i1);
    slab[(y0+2)*17 + kz] = make_float2(r2, i2);
    slab[(y0+3)*17 + kz] = make_float2(r3, i3);
  }
  __syncthreads();
  // stage 2: y-DFT (complex)
  {
    int kz = tid & 15, kyi = tid >> 4;
    float f = (float)(kyi < 8 ? kyi : kyi - 16);
    float ang = -PI2 * f * 0.015625f;
    float sw, cw; __sincosf(ang, &sw, &cw);
    float tr=1.f, ti=0.f, ar=0.f, ai=0.f;
    for (int y = 0; y < 64; ++y) {
      float2 v = slab[y*17 + kz];
      ar += v.x*tr - v.y*ti;
      ai += v.x*ti + v.y*tr;
      float nt = tr*cw - ti*sw; ti = tr*sw + ti*cw; tr = nt;
    }
    *(float2*)&T2[(size_t)blk*512 + (kyi*16 + kz)*2] = make_float2(ar, ai);
  }
}

// ---------------- K3: forward partial DFT along x ----------------
__global__ __launch_bounds__(256) void k3_dftx(const float* __restrict__ T2, float* __restrict__ xs) {
  __shared__ float slab[2048];
  int blk = blockIdx.x;
  int bc = blk >> 4, ky = blk & 15;
  int tid = threadIdx.x;
  for (int i = tid; i < 2048; i += 256) {
    int xr = i >> 5, rem = i & 31;
    slab[i] = T2[((size_t)(bc*64 + xr)*16 + ky)*32 + rem];
  }
  __syncthreads();
  int kz = tid & 15, kxi = tid >> 4;
  float f = (float)(kxi < 8 ? kxi : kxi - 16);
  float ang = -PI2 * f * 0.015625f;
  float sw, cw; __sincosf(ang, &sw, &cw);
  float tr=1.f, ti=0.f, ar=0.f, ai=0.f;
  for (int xr = 0; xr < 64; ++xr) {
    float2 v = *(const float2*)&slab[(xr*16 + kz)*2];
    ar += v.x*tr - v.y*ti;
    ai += v.x*ti + v.y*tr;
    float nt = tr*cw - ti*sw; ti = tr*sw + ti*cw; tr = nt;
  }
  *(float2*)&xs[(size_t)bc*8192 + (kxi*256 + ky*16 + kz)*2] = make_float2(ar, ai);
}

// ---------------- K4: project onto (shell, harmonic) basis ----------------
// grid 1024 = bc*16 + shell ; Yw rows are shell-sorted + wsh-premultiplied
__global__ __launch_bounds__(256) void k4_proj(const float* __restrict__ xs, const float* __restrict__ Yw,
    const int* __restrict__ order, const int* __restrict__ sstart, float* __restrict__ coeffs) {
  int blk = blockIdx.x; int bc = blk >> 4, s = blk & 15;
  int tid = threadIdx.x;
  int st = sstart[s], en = sstart[s+1];
  float ar[9], ai[9];
  #pragma unroll
  for (int l = 0; l < 9; ++l) { ar[l] = 0.f; ai[l] = 0.f; }
  for (int ii = st + tid; ii < en; ii += 256) {
    int m = order[ii];
    float2 v = *(const float2*)&xs[(size_t)bc*8192 + m*2];
    const float* yrow = Yw + (size_t)ii*10;
    #pragma unroll
    for (int l = 0; l < 9; ++l) {
      float yv = yrow[l];
      ar[l] += yv * v.x; ai[l] += yv * v.y;
    }
  }
  #pragma unroll
  for (int off = 32; off >= 1; off >>= 1) {
    #pragma unroll
    for (int l = 0; l < 9; ++l) {
      ar[l] += __shfl_down(ar[l], off, 64);
      ai[l] += __shfl_down(ai[l], off, 64);
    }
  }
  __shared__ float wred[4][18];
  int lane = tid & 63, wv = tid >> 6;
  if (lane == 0) {
    #pragma unroll
    for (int l = 0; l < 9; ++l) { wred[wv][l] = ar[l]; wred[wv][9 + l] = ai[l]; }
  }
  __syncthreads();
  if (tid < 18) {
    float v = wred[0][tid] + wred[1][tid] + wred[2][tid] + wred[3][tid];
    int l = tid % 9, ri = tid / 9;
    coeffs[((size_t)bc*144 + s*9 + l)*2 + ri] = v;
  }
}

// ---------------- K5: complex spectral conv + ifft normalization ----------------
__global__ __launch_bounds__(64) void k5_spec(const float* __restrict__ coeffs,
    const float* __restrict__ wsr, const float* __restrict__ wsi, float* __restrict__ coeffs2) {
  int blk = blockIdx.x;
  int b = blk / 144, sl = blk % 144;
  int o = threadIdx.x;
  if (o >= 32) return;
  float ar = 0.f, ai = 0.f;
  for (int i = 0; i < 32; ++i) {
    float cr = coeffs[((size_t)(b*32 + i)*144 + sl)*2];
    float ci = coeffs[((size_t)(b*32 + i)*144 + sl)*2 + 1];
    float wr = wsr[(sl*32 + i)*32 + o];
    float wi = wsi[(sl*32 + i)*32 + o];
    ar += cr*wr - ci*wi;
    ai += cr*wi + ci*wr;
  }
  const float sc = 1.0f / 262144.0f;
  coeffs2[((size_t)(b*32 + o)*144 + sl)*2]     = ar * sc;
  coeffs2[((size_t)(b*32 + o)*144 + sl)*2 + 1] = ai * sc;
}

// ---------------- K8: back-project (ex-K7) + inverse partial DFT along x ----------------
// grid 1024 = bo*16 + ky
__global__ __launch_bounds__(256) void k8_invx(const float* __restrict__ coeffs2,
    const float* __restrict__ Y, const int* __restrict__ shellOf, const float* __restrict__ wsh,
    float* __restrict__ U1) {
  __shared__ float slab[512];                 // [kx][kz] cplx for fixed ky
  __shared__ float c2s[288];
  int blk = blockIdx.x;
  int bo = blk >> 4, ky = blk & 15;
  int tid = threadIdx.x;
  for (int i = tid; i < 288; i += 256) c2s[i] = coeffs2[(size_t)bo*288 + i];
  __syncthreads();
  {
    int kx = tid >> 4, kz = tid & 15;
    int m = kx*256 + ky*16 + kz;
    int sh = shellOf[m];
    float w = wsh[sh];
    float ar = 0.f, ai = 0.f;
    #pragma unroll
    for (int l = 0; l < 9; ++l) {
      float yv = Y[l*4096 + m];
      ar += yv * c2s[(sh*9 + l)*2];
      ai += yv * c2s[(sh*9 + l)*2 + 1];
    }
    slab[kx*32 + kz*2]     = w * ar;
    slab[kx*32 + kz*2 + 1] = w * ai;
  }
  __syncthreads();
  int kz = tid & 15, grp = tid >> 4;
  float tr4[4], ti4[4], wr4[4], wi4[4], ar4[4], ai4[4];
  #pragma unroll
  for (int q = 0; q < 4; ++q) {
    int xx = grp + 16*q;
    float ang = PI2 * (float)xx * 0.015625f;
    __sincosf(ang, &wi4[q], &wr4[q]);
    tr4[q] = 1.f; ti4[q] = 0.f; ar4[q] = 0.f; ai4[q] = 0.f;
  }
  #pragma unroll
  for (int kx = 0; kx < 16; ++kx) {
    if (kx == 8) { ti4[0] = -ti4[0]; ti4[1] = -ti4[1]; ti4[2] = -ti4[2]; ti4[3] = -ti4[3]; }
    float2 v = *(const float2*)&slab[(kx*16 + kz)*2];
    #pragma unroll
    for (int q = 0; q < 4; ++q) {
      ar4[q] += v.x*tr4[q] - v.y*ti4[q];
      ai4[q] += v.x*ti4[q] + v.y*tr4[q];
      float nt = tr4[q]*wr4[q] - ti4[q]*wi4[q];
      ti4[q] = tr4[q]*wi4[q] + ti4[q]*wr4[q];
      tr4[q] = nt;
    }
  }
  #pragma unroll
  for (int q = 0; q < 4; ++q) {
    int xx = grp + 16*q;
    *(float2*)&U1[((size_t)(bo*64 + xx)*16 + ky)*32 + kz*2] = make_float2(ar4[q], ai4[q]);
  }
}

// ---------------- K9: inverse partial DFT along y -> packed bf16 U2 ----------------
// grid 4096 = bo*64 + x
__global__ __launch_bounds__(256) void k9_invy(const float* __restrict__ U1, unsigned int* __restrict__ U2pk) {
  __shared__ float slab[512];
  int blk = blockIdx.x;
  int tid = threadIdx.x;
  const float* src = U1 + (size_t)blk * 512;
  for (int i = tid; i < 512; i += 256) slab[i] = src[i];
  __syncthreads();
  int kz = tid & 15, grp = tid >> 4;
  float tr4[4], ti4[4], wr4[4], wi4[4], ar4[4], ai4[4];
  #pragma unroll
  for (int q = 0; q < 4; ++q) {
    int yy = grp + 16*q;
    float ang = PI2 * (float)yy * 0.015625f;
    __sincosf(ang, &wi4[q], &wr4[q]);
    tr4[q] = 1.f; ti4[q] = 0.f; ar4[q] = 0.f; ai4[q] = 0.f;
  }
  #pragma unroll
  for (int ky = 0; ky < 16; ++ky) {
    if (ky == 8) { ti4[0] = -ti4[0]; ti4[1] = -ti4[1]; ti4[2] = -ti4[2]; ti4[3] = -ti4[3]; }
    float2 v = *(const float2*)&slab[(ky*16 + kz)*2];
    #pragma unroll
    for (int q = 0; q < 4; ++q) {
      ar4[q] += v.x*tr4[q] - v.y*ti4[q];
      ai4[q] += v.x*ti4[q] + v.y*tr4[q];
      float nt = tr4[q]*wr4[q] - ti4[q]*wi4[q];
      ti4[q] = tr4[q]*wi4[q] + ti4[q]*wr4[q];
      tr4[q] = nt;
    }
  }
  unsigned int* dst = U2pk + (size_t)blk * 1024;
  #pragma unroll
  for (int q = 0; q < 4; ++q) {
    int yy = grp + 16*q;
    dst[yy*16 + kz] = pk2(ar4[q], ai4[q]);
  }
}

// ---------------- K10: MFMA inverse-z DFT + MFMA MLP + skips ----------------
// grid 4096 = ((b*64 + x)*32 + yblock) ; 2 y-lines, 256 threads
__global__ __launch_bounds__(256) void k10_final(
    const float* __restrict__ x, const unsigned int* __restrict__ U2pk,
    const float* __restrict__ ws,
    const float* __restrict__ w2r, const float* __restrict__ w2i,
    const float* __restrict__ b2r, const float* __restrict__ wgr,
    float* __restrict__ out) {
  const float* w1rt = ws + O_W1RT;  const float* w1it = ws + O_W1IT;
  const float* W1xr = ws + O_W1XR;  const float* W1xi = ws + O_W1XI;
  const float* b1pr = ws + O_B1PR;  const float* b1pi = ws + O_B1PI;

  __shared__ __hip_bfloat16 xlT[128*34];      // [row=(ya,z)][c] bf16, 8704 B
  __shared__ unsigned int xfT[128*33];        // packed bf16 {re,im} x_fno, 16896 B
  __shared__ unsigned int upk_hp[1280];       // phase1/2: Upk[(ya*32+c)*20+kz]; phase3: hpW

  int tid = threadIdx.x;
  int blk = blockIdx.x;
  int yb = blk & 31, bx = blk >> 5;
  int b = bx >> 6, xr = bx & 63;
  int y0 = yb * 2;

  // ---- Phase 1: coalesced staging ----
  for (int i = tid; i < 4096; i += 256) {
    int ya = i >> 11, c = (i >> 6) & 31, z = i & 63;
    float v = x[(size_t)(b*32 + c)*262144 + (size_t)xr*4096 + (size_t)(y0 + ya)*64 + z];
    xlT[((ya << 6) + z)*34 + c] = __float2bfloat16(v);
  }
  for (int e = tid; e < 1024; e += 256) {
    int kz = e & 15, c = (e >> 4) & 31, ya = e >> 9;
    upk_hp[(ya*32 + c)*20 + kz] =
        U2pk[((size_t)((b*32 + c)*64 + xr))*1024 + (size_t)(y0 + ya)*16 + kz];
  }
  __syncthreads();

  union U8 { short8 v; unsigned int u[4]; };
  f32x4 zacc = {0.f, 0.f, 0.f, 0.f};
  int lane = tid & 63, wv = tid >> 6;
  int p = lane & 15, q = lane >> 4;

  // ---- Phase 2: z-iDFT via MFMA.  xf = [cos|-sin ; sin|cos] @ [Ur;Ui] ----
  {
    int ya = wv >> 1;
    unsigned int sel = (q < 2) ? 0x05040100u : 0x07060302u;
    int j0 = (q & 1) * 8;
    U8 Bf[2];
    #pragma unroll
    for (int h = 0; h < 2; ++h) {
      int c = h*16 + p;
      const uint4* bp = (const uint4*)&upk_hp[(ya*32 + c)*20 + j0];
      uint4 A0 = bp[0], A1 = bp[1];
      Bf[h].u[0] = __builtin_amdgcn_perm(A0.y, A0.x, sel);
      Bf[h].u[1] = __builtin_amdgcn_perm(A0.w, A0.z, sel);
      Bf[h].u[2] = __builtin_amdgcn_perm(A1.y, A1.x, sel);
      Bf[h].u[3] = __builtin_amdgcn_perm(A1.w, A1.z, sel);
    }
    #pragma unroll
    for (int tt = 0; tt < 2; ++tt) {
      int t = wv*2 + tt;
      int zb = (t & 3) * 16;
      float zf = (float)(zb + p);
      U8 fAr, fAi;
      #pragma unroll
      for (int s = 0; s < 4; ++s) {
        int kk = 8*q + 2*s;
        int kz0 = kk & 15, kz1 = kz0 + 1;
        float f0 = (float)(kz0 < 8 ? kz0 : kz0 - 16);
        float f1 = (float)(kz1 < 8 ? kz1 : kz1 - 16);
        float s0, c0, s1, c1;
        __sincosf(PI2 * f0 * zf * 0.015625f, &s0, &c0);
        __sincosf(PI2 * f1 * zf * 0.015625f, &s1, &c1);
        bool hi = (q >= 2);
        float aR0 = hi ? -s0 : c0, aR1 = hi ? -s1 : c1;
        float aI0 = hi ?  c0 : s0, aI1 = hi ?  c1 : s1;
        fAr.u[s] = pk2(aR0, aR1);
        fAi.u[s] = pk2(aI0, aI1);
      }
      #pragma unroll
      for (int h = 0; h < 2; ++h) {
        f32x4 accR = __builtin_amdgcn_mfma_f32_16x16x32_bf16(fAr.v, Bf[h].v, zacc, 0, 0, 0);
        f32x4 accI = __builtin_amdgcn_mfma_f32_16x16x32_bf16(fAi.v, Bf[h].v, zacc, 0, 0, 0);
        #pragma unroll
        for (int r = 0; r < 4; ++r) {
          int row = ya*64 + zb + 4*q + r;
          xfT[row*33 + h*16 + p] = pk2(accR[r], accI[r]);
        }
      }
    }
  }
  __syncthreads();

  // ---- Phase 3: MFMA channel-mix MLP (upk_hp reused as per-wave H buffer) ----
  {
    unsigned int* hpW = upk_hp;
    int wb = wv * 272;

    U8 fW1r, fW1i, fW1iN, fW1xr, fW1xi, fW2[2];
    #pragma unroll
    for (int s = 0; s < 4; ++s) {
      int c0 = 8*q + 2*s, c1 = c0 + 1;
      fW1r.u[s]  = pk2(w1rt[c0*16 + p], w1rt[c1*16 + p]);
      fW1i.u[s]  = pk2(w1it[c0*16 + p], w1it[c1*16 + p]);
      fW1iN.u[s] = fW1i.u[s] ^ 0x80008000u;
      fW1xr.u[s] = pk2(W1xr[c0*16 + p], W1xr[c1*16 + p]);
      fW1xi.u[s] = pk2(W1xi[c0*16 + p], W1xi[c1*16 + p]);
    }
    #pragma unroll
    for (int mt = 0; mt < 2; ++mt) {
      int o = mt*16 + p;
      #pragma unroll
      for (int s = 0; s < 4; ++s) {
        int k0 = 8*q + 2*s;
        float a  = (k0   < 16) ? w2r[o*16 + k0]      : -w2i[o*16 + k0 - 16];
        float bb = (k0+1 < 16) ? w2r[o*16 + k0 + 1]  : -w2i[o*16 + k0 - 15];
        fW2[mt].u[s] = pk2(a, bb);
      }
    }
    float4 b1r4 = *(const float4*)(b1pr + 4*q);
    float4 b1i4 = *(const float4*)(b1pi + 4*q);
    float b1ra[4] = {b1r4.x, b1r4.y, b1r4.z, b1r4.w};
    float b1ia[4] = {b1i4.x, b1i4.y, b1i4.z, b1i4.w};
    float b2a[2][4], wga[2][4];
    #pragma unroll
    for (int mt = 0; mt < 2; ++mt) {
      float4 t0 = *(const float4*)(b2r + mt*16 + 4*q);
      float4 t1 = *(const float4*)(wgr + mt*16 + 4*q);
      b2a[mt][0]=t0.x; b2a[mt][1]=t0.y; b2a[mt][2]=t0.z; b2a[mt][3]=t0.w;
      wga[mt][0]=t1.x; wga[mt][1]=t1.y; wga[mt][2]=t1.z; wga[mt][3]=t1.w;
    }

    const unsigned int* xlW = (const unsigned int*)xlT;

    for (int tt = 0; tt < 2; ++tt) {
      int tile = wv*2 + tt;
      int ya = tile >> 2, zg = tile & 3;
      int row = ya*64 + zg*16 + p;

      unsigned int w8[8];
      #pragma unroll
      for (int jj = 0; jj < 8; ++jj) w8[jj] = xfT[row*33 + 8*q + jj];
      U8 FR, FI, XV;
      #pragma unroll
      for (int s = 0; s < 4; ++s) {
        FR.u[s] = __builtin_amdgcn_perm(w8[2*s+1], w8[2*s], 0x05040100u);
        FI.u[s] = __builtin_amdgcn_perm(w8[2*s+1], w8[2*s], 0x07060302u);
        XV.u[s] = xlW[row*17 + 4*q + s];
      }

      f32x4 accR = zacc, accI = zacc;
      accR = __builtin_amdgcn_mfma_f32_16x16x32_bf16(fW1r.v,  FR.v, accR, 0, 0, 0);
      accR = __builtin_amdgcn_mfma_f32_16x16x32_bf16(fW1iN.v, FI.v, accR, 0, 0, 0);
      accR = __builtin_amdgcn_mfma_f32_16x16x32_bf16(fW1xr.v, XV.v, accR, 0, 0, 0);
      accI = __builtin_amdgcn_mfma_f32_16x16x32_bf16(fW1r.v,  FI.v, accI, 0, 0, 0);
      accI = __builtin_amdgcn_mfma_f32_16x16x32_bf16(fW1i.v,  FR.v, accI, 0, 0, 0);
      accI = __builtin_amdgcn_mfma_f32_16x16x32_bf16(fW1xi.v, XV.v, accI, 0, 0, 0);

      float hr_[4], hi_[4];
      #pragma unroll
      for (int r = 0; r < 4; ++r) {
        hr_[r] = geluf(accR[r] + b1ra[r]);
        hi_[r] = geluf(accI[r] + b1ia[r]);
      }
      hpW[wb + 17*p + 2*q]         = pk2(hr_[0], hr_[1]);
      hpW[wb + 17*p + 2*q + 1]     = pk2(hr_[2], hr_[3]);
      hpW[wb + 17*p + 8 + 2*q]     = pk2(hi_[0], hi_[1]);
      hpW[wb + 17*p + 8 + 2*q + 1] = pk2(hi_[2], hi_[3]);

      U8 FH;
      #pragma unroll
      for (int s = 0; s < 4; ++s) FH.u[s] = hpW[wb + 17*p + 4*q + s];

      #pragma unroll
      for (int mt = 0; mt < 2; ++mt) {
        f32x4 accO = __builtin_amdgcn_mfma_f32_16x16x32_bf16(fW2[mt].v, FH.v, zacc, 0, 0, 0);
        #pragma unroll
        for (int r = 0; r < 4; ++r) {
          int o = mt*16 + q*4 + r;
          int z = zg*16 + p;
          float xv = __bfloat162float(xlT[row*34 + o]);
          out[(size_t)(b*32 + o)*262144 + (size_t)xr*4096 + (size_t)(y0 + ya)*64 + z]
              = accO[r] + b2a[mt][r] + wga[mt][r]*xv;
        }
      }
    }
  }
}

// ---------------- launch ----------------
extern "C" void kernel_launch(void* const* d_in, const int* in_sizes, int n_in,
                              void* d_out, int out_size, void* d_ws, size_t ws_size,
                              hipStream_t stream) {
  (void)in_sizes; (void)n_in; (void)out_size; (void)ws_size;
  const float* x   = (const float*)d_in[0];
  const float* wfr = (const float*)d_in[1];
  const float* wfi = (const float*)d_in[2];
  const float* bfr = (const float*)d_in[3];
  const float* bfi = (const float*)d_in[4];
  const float* wgr = (const float*)d_in[5];
  const float* wsr = (const float*)d_in[7];
  const float* wsi = (const float*)d_in[8];
  const float* w1r = (const float*)d_in[9];
  const float* w1i = (const float*)d_in[10];
  const float* b1r = (const float*)d_in[11];
  const float* b1i = (const float*)d_in[12];
  const float* w2r = (const float*)d_in[13];
  const float* w2i = (const float*)d_in[14];
  const float* b2r = (const float*)d_in[15];
  float* out = (float*)d_out;
  float* ws  = (float*)d_ws;

  unsigned int* U2pk = (unsigned int*)(ws + O_T1);
  float* U1      = ws + O_T2;
  float* T2      = ws + O_T2;    // reused: T2 consumed by k3 before k8 writes U1
  float* xs      = ws + O_XS;
  float* coeffs  = ws + O_COEF;
  float* coeffs2 = ws + O_COEF2;
  float* Y       = ws + O_Y;
  float* Yw      = ws + O_YW;
  int* shellOf   = (int*)(ws + O_SHELL);
  int* order     = (int*)(ws + O_ORDER);
  int* sstart    = (int*)(ws + O_SSTART);
  float* wsh     = ws + O_WSH;

  hipLaunchKernelGGL(k0_init,  dim3(1),    dim3(256), 0, stream, wfr, wfi, bfr, bfi, w1r, w1i, b1r, b1i, ws);
  hipLaunchKernelGGL(k12_fwd,  dim3(4096), dim3(256), 0, stream, x, T2);
  hipLaunchKernelGGL(k3_dftx,  dim3(1024), dim3(256), 0, stream, T2, xs);
  hipLaunchKernelGGL(k4_proj,  dim3(1024), dim3(256), 0, stream, xs, Yw, order, sstart, coeffs);
  hipLaunchKernelGGL(k5_spec,  dim3(288),  dim3(64),  0, stream, coeffs, wsr, wsi, coeffs2);
  hipLaunchKernelGGL(k8_invx,  dim3(1024), dim3(256), 0, stream, coeffs2, Y, shellOf, wsh, U1);
  hipLaunchKernelGGL(k9_invy,  dim3(4096), dim3(256), 0, stream, U1, U2pk);
  hipLaunchKernelGGL(k10_final,dim3(4096), dim3(256), 0, stream, x, U2pk, ws, w2r, w2i, b2r, wgr, out);
}